// Round 7
// baseline (509.268 us; speedup 1.0000x reference)
//
#include <hip/hip_runtime.h>
#include <hip/hip_bf16.h>
#include <stdint.h>

// Problem constants
#define BB 2
#define LL 1024
#define DMODEL 2048
#define DINNER 4096
#define DSTATE 16
#define DTRANK 128
#define XDBL_LD 256   // x_proj rows padded 160 -> 256
#define CHUNK 64
#define NCH (LL / CHUNK)   // 16

typedef unsigned short ushort;
using short8 = __attribute__((ext_vector_type(8))) short;
using f32x4  = __attribute__((ext_vector_type(4))) float;
using us4    = __attribute__((ext_vector_type(4))) ushort;

__device__ __forceinline__ float bf2f(ushort u) {
    union { uint32_t i; float f; } v; v.i = ((uint32_t)u) << 16; return v.f;
}
__device__ __forceinline__ ushort f2bf(float f) {
    union { float f; uint32_t i; } v; v.f = f;
    uint32_t lsb = (v.i >> 16) & 1u;
    uint32_t r = v.i + 0x7FFFu + lsb;   // RNE
    return (ushort)(r >> 16);
}

// Async global->LDS, 16B per lane (lane-ordered, unpadded LDS dest).
__device__ __forceinline__ void glds16(const ushort* g, ushort* l) {
    __builtin_amdgcn_global_load_lds(
        (const __attribute__((address_space(1))) void*)g,
        (__attribute__((address_space(3))) void*)l,
        16, 0, 0);
}

// ---------------------------------------------------------------------------
// Fused f32->bf16 conversion of all weights/activations + x_proj zero-pad.
// ---------------------------------------------------------------------------
__global__ __launch_bounds__(256) void cvt_all(
    const float4* __restrict__ hidden, const float4* __restrict__ inproj,
    const float4* __restrict__ dtw, const float4* __restrict__ outp,
    const float4* __restrict__ xproj,
    us4* __restrict__ hid_h, us4* __restrict__ inp_h, us4* __restrict__ dtp_h,
    us4* __restrict__ outp_h, us4* __restrict__ xpp)
{
    long i = (long)blockIdx.x * 256 + threadIdx.x;
    const float4* src; us4* dst; long j;
    if (i < 1048576)      { src = hidden; dst = hid_h;  j = i; }
    else if (i < 5242880) { src = inproj; dst = inp_h;  j = i - 1048576; }
    else if (i < 5373952) { src = dtw;    dst = dtp_h;  j = i - 5242880; }
    else if (i < 7471104) { src = outp;   dst = outp_h; j = i - 5373952; }
    else {
        j = i - 7471104; dst = xpp;
        if (j >= 163840) { us4 z = {0, 0, 0, 0}; dst[j] = z; return; }
        src = xproj;
    }
    float4 v = src[j];
    us4 o; o.x = f2bf(v.x); o.y = f2bf(v.y); o.z = f2bf(v.z); o.w = f2bf(v.w);
    dst[j] = o;
}

// ---------------------------------------------------------------------------
// 256x256 NT GEMM (r4 best variant: T2 swizzle + setprio + B-frag dedup,
// one __syncthreads per K-tile). 67 us / 1024 TF on gemm1 — local optimum
// after 6 schedule experiments (counted-vmcnt, SBAR, BK32 all regressed).
// ---------------------------------------------------------------------------
template <bool WF, bool WH>
__global__ __launch_bounds__(512, 2) void gemm_nt256(
    const ushort* __restrict__ A, int lda,
    const ushort* __restrict__ Bm, int ldb,
    float* __restrict__ Cf, ushort* __restrict__ Ch, int ldc,
    int K)
{
    __shared__ __align__(16) ushort sA[2][256 * 64];   // 2 x 32 KB
    __shared__ __align__(16) ushort sB[2][256 * 64];   // 2 x 32 KB

    const int tid  = threadIdx.x;
    const int lane = tid & 63;
    const int wave = tid >> 6;          // 0..7
    const int wr   = wave >> 2;         // 0..1 (M half)
    const int wcol = wave & 3;          // 0..3 (N quarter)
    const int lrow = lane & 15;
    const int lg   = lane >> 4;         // 0..3
    const int s7   = lane & 7;
    const int kb0 = ((0 + lg) ^ s7) << 4;
    const int kb1 = ((4 + lg) ^ s7) << 4;

    const int NT = gridDim.x, MT = gridDim.y;
    int mt, nt;
    if ((NT & 7) == 0) {
        int lin   = blockIdx.y * NT + blockIdx.x;
        int strip = NT >> 3;
        int xcd   = lin & 7;
        int idx   = lin >> 3;
        nt = xcd * strip + (idx % strip);
        mt = idx / strip;
    } else { mt = blockIdx.y; nt = blockIdx.x; }
    const long m0 = (long)mt * 256;
    const long n0 = (long)nt * 256;

    const long zoff = (long)blockIdx.z;
    A  += zoff * (long)K;
    Bm += zoff * (long)K;
    const long Mrows = (long)MT * 256;
    if (WF) Cf += zoff * Mrows * (long)ldc;

    f32x4 acc[8][4] = {};

    const int sr   = tid >> 3;                       // 0..63
    const int scol = (((tid & 7) ^ (sr & 7)) << 3);  // element col 0..56
    const ushort* Ag = A  + (m0 + sr) * (long)lda + scol;
    const ushort* Bg = Bm + (n0 + sr) * (long)ldb + scol;

    const int NKT = K >> 6;

    {
        ushort* dA0 = &sA[0][0] + tid * 8;
        ushort* dB0 = &sB[0][0] + tid * 8;
        #pragma unroll
        for (int c = 0; c < 4; ++c) {
            glds16(Ag + (c * 64) * (long)lda, dA0 + c * 4096);
            glds16(Bg + (c * 64) * (long)ldb, dB0 + c * 4096);
        }
    }
    __syncthreads();

    const int arow0 = (wr * 128 + lrow) * 128;
    const int brow0 = (wcol * 64 + lrow) * 128;

    for (int kt = 0; kt < NKT; ++kt) {
        const int p = kt & 1;
        const char* sap = (const char*)&sA[p][0];
        const char* sbp = (const char*)&sB[p][0];
        ushort* dA = &sA[p ^ 1][0] + tid * 8;
        ushort* dB = &sB[p ^ 1][0] + tid * 8;
        const long kn = (long)(kt + 1) << 6;
        const bool pf = (kt + 1 < NKT);

        short8 bf[4][2];
        #pragma unroll
        for (int j = 0; j < 4; ++j) {
            const int bb = brow0 + (j * 16) * 128;
            bf[j][0] = *(const short8*)(sbp + bb + kb0);
            bf[j][1] = *(const short8*)(sbp + bb + kb1);
        }

        #pragma unroll
        for (int mh = 0; mh < 2; ++mh) {
            short8 af[4][2];
            #pragma unroll
            for (int i4 = 0; i4 < 4; ++i4) {
                const int ab = arow0 + (mh * 64 + i4 * 16) * 128;
                af[i4][0] = *(const short8*)(sap + ab + kb0);
                af[i4][1] = *(const short8*)(sap + ab + kb1);
            }
            if (pf) {
                if (mh == 0) {
                    #pragma unroll
                    for (int c = 0; c < 4; ++c)
                        glds16(Ag + (c * 64) * (long)lda + kn, dA + c * 4096);
                } else {
                    #pragma unroll
                    for (int c = 0; c < 4; ++c)
                        glds16(Bg + (c * 64) * (long)ldb + kn, dB + c * 4096);
                }
            }
            __builtin_amdgcn_s_setprio(1);
            #pragma unroll
            for (int ks = 0; ks < 2; ++ks)
                #pragma unroll
                for (int i4 = 0; i4 < 4; ++i4)
                    #pragma unroll
                    for (int j = 0; j < 4; ++j)
                        acc[mh * 4 + i4][j] =
                            __builtin_amdgcn_mfma_f32_16x16x32_bf16(
                                af[i4][ks], bf[j][ks],
                                acc[mh * 4 + i4][j], 0, 0, 0);
            __builtin_amdgcn_s_setprio(0);
        }
        __syncthreads();
    }

    const int r0 = (lane >> 4) * 4;
    const int c0 = lane & 15;
    #pragma unroll
    for (int i = 0; i < 8; ++i) {
        #pragma unroll
        for (int j = 0; j < 4; ++j) {
            const long col = n0 + wcol * 64 + j * 16 + c0;
            #pragma unroll
            for (int r = 0; r < 4; ++r) {
                const long row = m0 + wr * 128 + i * 16 + r0 + r;
                const float v = acc[i][j][r];
                const long idx = row * (long)ldc + col;
                if (WF) Cf[idx] = v;
                if (WH) Ch[idx] = f2bf(v);
            }
        }
    }
}

// ---------------------------------------------------------------------------
// NEW: 128x128 tile, 4 waves (2x2 of 64x64), BK=64, double-buffered glds
// prefetch + T2 swizzle (identical 128-B-row geometry to gemm_nt256 ->
// conflicts 0) + setprio, one __syncthreads per K-tile. 64 KB LDS ->
// 2 blocks/CU. Purpose: gemm6 at z=1, grid 16x16 = 256 wg exactly fills the
// chip with full-K accumulation and DIRECT f32 output write — eliminates
// split-K partials (128 MiB traffic) and the reduce dispatch.
// ---------------------------------------------------------------------------
template <bool WF, bool WH>
__global__ __launch_bounds__(256, 2) void gemm_nt128d(
    const ushort* __restrict__ A, int lda,
    const ushort* __restrict__ Bm, int ldb,
    float* __restrict__ Cf, ushort* __restrict__ Ch, int ldc,
    int K)
{
    __shared__ __align__(16) ushort sA[2][128 * 64];   // 2 x 16 KB
    __shared__ __align__(16) ushort sB[2][128 * 64];   // 2 x 16 KB

    const int tid  = threadIdx.x;
    const int lane = tid & 63;
    const int wave = tid >> 6;          // 0..3
    const int wr   = wave >> 1;         // 0..1 (M half, 64 rows)
    const int wc   = wave & 1;          // 0..1 (N half, 64 cols)
    const int lrow = lane & 15;
    const int lg   = lane >> 4;         // 0..3
    const int s7   = lane & 7;
    const int kb0 = ((0 + lg) ^ s7) << 4;
    const int kb1 = ((4 + lg) ^ s7) << 4;

    // XCD-aware tile swizzle
    const int NT = gridDim.x, MT = gridDim.y;
    int mt, nt;
    if ((NT & 7) == 0) {
        int lin   = blockIdx.y * NT + blockIdx.x;
        int strip = NT >> 3;
        int xcd   = lin & 7;
        int idx   = lin >> 3;
        nt = xcd * strip + (idx % strip);
        mt = idx / strip;
    } else { mt = blockIdx.y; nt = blockIdx.x; }
    const long m0 = (long)mt * 128;
    const long n0 = (long)nt * 128;

    f32x4 acc[4][4] = {};

    // staging: 128 rows x 64 cols bf16 = 16 KB = 256 thr x 4 glds16.
    // thread t: row-in-load sr = t>>3 (0..31), LDS slot t&7; load c covers
    // rows [32c, 32c+32). LDS row = 32c + sr, (row&7) == (sr&7) -> inverse
    // swizzle on the global source column only:
    const int sr   = tid >> 3;                       // 0..31
    const int scol = (((tid & 7) ^ (sr & 7)) << 3);  // element col 0..56
    const ushort* Ag = A  + (m0 + sr) * (long)lda + scol;
    const ushort* Bg = Bm + (n0 + sr) * (long)ldb + scol;

    const int NKT = K >> 6;

    // prologue: stage tile 0 into buf 0
    {
        ushort* dA0 = &sA[0][0] + tid * 8;
        ushort* dB0 = &sB[0][0] + tid * 8;
        #pragma unroll
        for (int c = 0; c < 4; ++c) {
            glds16(Ag + (c * 32) * (long)lda, dA0 + c * 2048);
            glds16(Bg + (c * 32) * (long)ldb, dB0 + c * 2048);
        }
    }
    __syncthreads();

    const int arow0 = (wr * 64 + lrow) * 128;   // byte base of A rows
    const int brow0 = (wc * 64 + lrow) * 128;   // byte base of B rows

    for (int kt = 0; kt < NKT; ++kt) {
        const int p = kt & 1;
        const char* sap = (const char*)&sA[p][0];
        const char* sbp = (const char*)&sB[p][0];
        ushort* dA = &sA[p ^ 1][0] + tid * 8;
        ushort* dB = &sB[p ^ 1][0] + tid * 8;
        const long kn = (long)(kt + 1) << 6;
        const bool pf = (kt + 1 < NKT);

        short8 af[4][2], bf[4][2];
        #pragma unroll
        for (int i = 0; i < 4; ++i) {
            const int ab = arow0 + (i * 16) * 128;
            af[i][0] = *(const short8*)(sap + ab + kb0);
            af[i][1] = *(const short8*)(sap + ab + kb1);
        }
        #pragma unroll
        for (int j = 0; j < 4; ++j) {
            const int bb = brow0 + (j * 16) * 128;
            bf[j][0] = *(const short8*)(sbp + bb + kb0);
            bf[j][1] = *(const short8*)(sbp + bb + kb1);
        }

        // prefetch next tile (drained by tile-end __syncthreads; stalls
        // covered by the co-resident block)
        if (pf) {
            #pragma unroll
            for (int c = 0; c < 4; ++c) {
                glds16(Ag + (c * 32) * (long)lda + kn, dA + c * 2048);
                glds16(Bg + (c * 32) * (long)ldb + kn, dB + c * 2048);
            }
        }

        __builtin_amdgcn_s_setprio(1);
        #pragma unroll
        for (int ks = 0; ks < 2; ++ks)
            #pragma unroll
            for (int i = 0; i < 4; ++i)
                #pragma unroll
                for (int j = 0; j < 4; ++j)
                    acc[i][j] = __builtin_amdgcn_mfma_f32_16x16x32_bf16(
                        af[i][ks], bf[j][ks], acc[i][j], 0, 0, 0);
        __builtin_amdgcn_s_setprio(0);

        __syncthreads();
    }

    // C/D mapping: col = lane&15, row = (lane>>4)*4 + reg (verified layout).
    const int r0 = (lane >> 4) * 4;
    const int c0 = lane & 15;
    #pragma unroll
    for (int i = 0; i < 4; ++i) {
        #pragma unroll
        for (int j = 0; j < 4; ++j) {
            const long col = n0 + wc * 64 + j * 16 + c0;
            #pragma unroll
            for (int r = 0; r < 4; ++r) {
                const long row = m0 + wr * 64 + i * 16 + r0 + r;
                const float v = acc[i][j][r];
                const long idx = row * (long)ldc + col;
                if (WF) Cf[idx] = v;
                if (WH) Ch[idx] = f2bf(v);
            }
        }
    }
}

// ---------------------------------------------------------------------------
// NT GEMM: 128x128 tile, 2-phase (kept for the small GEMMs: x_dbl, delta).
// ---------------------------------------------------------------------------
template <int EPI, bool WF, bool WH>
__global__ __launch_bounds__(256) void gemm_nt(
    const ushort* __restrict__ A, int lda,
    const ushort* __restrict__ Bm, int ldb,
    float* __restrict__ Cf, ushort* __restrict__ Ch, int ldc,
    int K, const float* __restrict__ bias)
{
    __shared__ __align__(16) ushort sA[128 * 64];   // 16 KB
    __shared__ __align__(16) ushort sB[128 * 64];   // 16 KB

    const int tid  = threadIdx.x;
    const int lane = tid & 63;
    const int wave = tid >> 6;
    const int wr = wave >> 1, wc = wave & 1;

    const int NT = gridDim.x, MT = gridDim.y;
    int mt, nt;
    if ((NT & 7) == 0) {
        int lin   = blockIdx.y * NT + blockIdx.x;
        int strip = NT >> 3;
        int xcd   = lin & 7;
        int idx   = lin >> 3;
        nt = xcd * strip + (idx % strip);
        mt = idx / strip;
    } else { mt = blockIdx.y; nt = blockIdx.x; }
    const long m0 = (long)mt * 128;
    const long n0 = (long)nt * 128;

    const long zoff = (long)blockIdx.z;
    A  += zoff * (long)K;
    Bm += zoff * (long)K;
    const long Mrows = (long)MT * 128;
    if (WF) Cf += zoff * Mrows * (long)ldc;
    if (WH) Ch += zoff * Mrows * (long)ldc;

    f32x4 acc[4][4] = {};

    const int lrow = lane & 15;
    const int lko  = (lane >> 4) << 3;

    const int sr = tid >> 3;            // 0..31
    const int sc = (tid & 7) << 3;      // element col 0..56
    const ushort* Ag = A  + (m0 + sr) * (long)lda + sc;
    const ushort* Bg = Bm + (n0 + sr) * (long)ldb + sc;
    ushort* lA = sA + tid * 8;
    ushort* lB = sB + tid * 8;

    for (int k0 = 0; k0 < K; k0 += 64) {
        __syncthreads();
        #pragma unroll
        for (int c = 0; c < 4; ++c) {
            glds16(Ag + (c * 32) * (long)lda + k0, lA + c * 2048);
            glds16(Bg + (c * 32) * (long)ldb + k0, lB + c * 2048);
        }
        __syncthreads();

        #pragma unroll
        for (int ks = 0; ks < 2; ++ks) {
            short8 af[4], bf[4];
            #pragma unroll
            for (int i = 0; i < 4; ++i)
                af[i] = *(const short8*)&sA[(wr * 64 + i * 16 + lrow) * 64 + ks * 32 + lko];
            #pragma unroll
            for (int j = 0; j < 4; ++j)
                bf[j] = *(const short8*)&sB[(wc * 64 + j * 16 + lrow) * 64 + ks * 32 + lko];

            #pragma unroll
            for (int i = 0; i < 4; ++i)
                #pragma unroll
                for (int j = 0; j < 4; ++j)
                    acc[i][j] = __builtin_amdgcn_mfma_f32_16x16x32_bf16(
                        af[i], bf[j], acc[i][j], 0, 0, 0);
        }
    }

    const int r0 = (lane >> 4) * 4;
    const int c0 = lane & 15;
    #pragma unroll
    for (int i = 0; i < 4; ++i) {
        #pragma unroll
        for (int j = 0; j < 4; ++j) {
            long col = n0 + wc * 64 + j * 16 + c0;
            float bv = 0.f;
            if (EPI == 1) bv = bias[col];
            #pragma unroll
            for (int r = 0; r < 4; ++r) {
                long row = m0 + wr * 64 + i * 16 + r0 + r;
                float v = acc[i][j][r];
                if (EPI == 1) {
                    v += bv;
                    v = (v > 20.f) ? v : log1pf(__expf(v));  // softplus
                }
                long idx = row * (long)ldc + col;
                if (WF) Cf[idx] = v;
                if (WH) Ch[idx] = f2bf(v);
            }
        }
    }
}

// ---------------------------------------------------------------------------
// Sum NZ per-split partials; write f32 and optionally bf16.
// ---------------------------------------------------------------------------
template <int NZ, bool WH_>
__global__ __launch_bounds__(256) void reduce_k(
    const float4* __restrict__ parts, long stride4, int n4,
    float4* __restrict__ outF, us4* __restrict__ outH)
{
    int i = blockIdx.x * 256 + threadIdx.x;
    if (i >= n4) return;
    float4 s = parts[i];
    #pragma unroll
    for (int z = 1; z < NZ; ++z) {
        float4 v = parts[(long)z * stride4 + i];
        s.x += v.x; s.y += v.y; s.z += v.z; s.w += v.w;
    }
    if (outF) outF[i] = s;
    if (WH_) {
        us4 o; o.x = f2bf(s.x); o.y = f2bf(s.y); o.z = f2bf(s.z); o.w = f2bf(s.w);
        outH[i] = o;
    }
}

// ---------------------------------------------------------------------------
// Depthwise causal conv(4) + bias + SiLU.
// ---------------------------------------------------------------------------
__global__ __launch_bounds__(256) void conv_silu_kernel(
    const ushort* __restrict__ xz,
    const float* __restrict__ cw,
    const float* __restrict__ cb,
    ushort* __restrict__ xc)
{
    int gid = blockIdx.x * 256 + threadIdx.x;   // over 2048*4096
    int d  = gid & (DINNER - 1);
    int rl = gid >> 12;
    int l  = rl & (LL - 1);
    float acc = cb[d];
    #pragma unroll
    for (int j = 0; j < 4; ++j) {
        int li = l - 3 + j;
        if (li >= 0)
            acc += cw[d * 4 + j] * bf2f(xz[(long)(rl - 3 + j) * 8192 + d]);
    }
    float s = acc / (1.f + __expf(-acc));
    xc[gid] = f2bf(s);
}

// ---------------------------------------------------------------------------
// Chunked selective scan (3 phases).
// ---------------------------------------------------------------------------
__global__ __launch_bounds__(256) void scan_p1(
    const ushort* __restrict__ delta,
    const ushort* __restrict__ xc,
    const float*  __restrict__ xdbl,
    const float*  __restrict__ A_log,
    float* __restrict__ Hbuf,
    float* __restrict__ sumdt_buf)
{
    __shared__ float sB[CHUNK * 16];
    const int tid = threadIdx.x;
    const int k = blockIdx.y, b = blockIdx.z;
    const int d = blockIdx.x * 256 + tid;
    const int row0 = b * LL + k * CHUNK;

    #pragma unroll
    for (int i = 0; i < 4; ++i) {
        int idx = i * 256 + tid;                 // = t*16 + s
        sB[idx] = xdbl[(long)(row0 + (idx >> 4)) * XDBL_LD + DTRANK + (idx & 15)];
    }
    __syncthreads();

    float A[DSTATE];
    const float4* Ap = (const float4*)(A_log + d * DSTATE);
    #pragma unroll
    for (int i = 0; i < 4; ++i) {
        float4 v = Ap[i];
        A[i*4+0] = -__expf(v.x); A[i*4+1] = -__expf(v.y);
        A[i*4+2] = -__expf(v.z); A[i*4+3] = -__expf(v.w);
    }

    float H[DSTATE];
    #pragma unroll
    for (int s = 0; s < DSTATE; ++s) H[s] = 0.f;
    float sumdt = 0.f;

    for (int t = 0; t < CHUNK; ++t) {
        const long row = row0 + t;
        const float dt = bf2f(delta[row * DINNER + d]);
        const float xv = bf2f(xc[row * DINNER + d]);
        const float dx = dt * xv;
        sumdt += dt;
        #pragma unroll
        for (int s = 0; s < DSTATE; ++s) {
            float dA = __expf(dt * A[s]);
            H[s] = H[s] * dA + dx * sB[t * 16 + s];
        }
    }

    const long o = ((long)(b * NCH + k) * DINNER + d) * DSTATE;
    float4* Ho = (float4*)(Hbuf + o);
    #pragma unroll
    for (int i = 0; i < 4; ++i) {
        float4 v; v.x = H[i*4+0]; v.y = H[i*4+1]; v.z = H[i*4+2]; v.w = H[i*4+3];
        Ho[i] = v;
    }
    sumdt_buf[(b * NCH + k) * DINNER + d] = sumdt;
}

__global__ __launch_bounds__(256) void scan_p2(
    const float* __restrict__ A_log,
    const float* __restrict__ sumdt_buf,
    float* __restrict__ Hbuf)
{
    int gid = blockIdx.x * 256 + threadIdx.x;   // 131072 = 2*4096*16
    int b = gid >> 16;
    int rem = gid & 65535;
    int d = rem >> 4, s = rem & 15;
    float A = -__expf(A_log[d * DSTATE + s]);
    float h = 0.f;
    for (int k = 0; k < NCH; ++k) {
        long idx = ((long)(b * NCH + k) * DINNER + d) * DSTATE + s;
        float Hk = Hbuf[idx];
        float sd = sumdt_buf[(b * NCH + k) * DINNER + d];
        Hbuf[idx] = h;
        h = h * __expf(A * sd) + Hk;
    }
}

__global__ __launch_bounds__(256) void scan_p3(
    const ushort* __restrict__ delta,
    const ushort* __restrict__ xc,
    const float*  __restrict__ xdbl,
    const ushort* __restrict__ xz,
    const float*  __restrict__ A_log,
    const float*  __restrict__ Dp,
    const float*  __restrict__ hin,
    ushort* __restrict__ y)
{
    __shared__ float sBC[CHUNK * 32];
    const int tid = threadIdx.x;
    const int k = blockIdx.y, b = blockIdx.z;
    const int d = blockIdx.x * 256 + tid;
    const int row0 = b * LL + k * CHUNK;

    #pragma unroll
    for (int i = 0; i < 8; ++i) {
        int idx = i * 256 + tid;                 // = t*32 + c
        sBC[idx] = xdbl[(long)(row0 + (idx >> 5)) * XDBL_LD + DTRANK + (idx & 31)];
    }
    __syncthreads();

    float A[DSTATE];
    const float4* Ap = (const float4*)(A_log + d * DSTATE);
    #pragma unroll
    for (int i = 0; i < 4; ++i) {
        float4 v = Ap[i];
        A[i*4+0] = -__expf(v.x); A[i*4+1] = -__expf(v.y);
        A[i*4+2] = -__expf(v.z); A[i*4+3] = -__expf(v.w);
    }
    const float Dd = Dp[d];

    float h[DSTATE];
    const float4* Hp = (const float4*)(hin + ((long)(b * NCH + k) * DINNER + d) * DSTATE);
    #pragma unroll
    for (int i = 0; i < 4; ++i) {
        float4 v = Hp[i];
        h[i*4+0] = v.x; h[i*4+1] = v.y; h[i*4+2] = v.z; h[i*4+3] = v.w;
    }

    for (int t = 0; t < CHUNK; ++t) {
        const long row = row0 + t;
        const float dt = bf2f(delta[row * DINNER + d]);
        const float xv = bf2f(xc[row * DINNER + d]);
        const float dx = dt * xv;
        float yt = 0.f;
        #pragma unroll
        for (int s = 0; s < DSTATE; ++s) {
            float dA = __expf(dt * A[s]);
            h[s] = h[s] * dA + dx * sBC[t * 32 + s];
            yt += h[s] * sBC[t * 32 + 16 + s];
        }
        yt += xv * Dd;
        const float zv = bf2f(xz[row * 8192 + DINNER + d]);
        yt *= zv / (1.f + __expf(-zv));
        y[row * DINNER + d] = f2bf(yt);
    }
}

// ---------------------------------------------------------------------------
extern "C" void kernel_launch(void* const* d_in, const int* in_sizes, int n_in,
                              void* d_out, int out_size, void* d_ws, size_t ws_size,
                              hipStream_t stream)
{
    const float* hidden    = (const float*)d_in[0];
    const float* in_proj   = (const float*)d_in[1];
    const float* conv_w    = (const float*)d_in[2];
    const float* conv_b    = (const float*)d_in[3];
    const float* x_proj    = (const float*)d_in[4];
    const float* dt_proj_w = (const float*)d_in[5];
    const float* dt_proj_b = (const float*)d_in[6];
    const float* A_log     = (const float*)d_in[7];
    const float* Dp        = (const float*)d_in[8];
    const float* out_proj  = (const float*)d_in[9];
    float* out = (float*)d_out;

    // Workspace layout (bytes, all 16B aligned)
    char* ws = (char*)d_ws;
    ushort* xz_h    = (ushort*)(ws);                // 32 MiB  (dead after scan_p3)
    ushort* xc      = (ushort*)(ws + 33554432);     // 16 MiB  (dead after scan_p3)
    ushort* xpp     = (ushort*)(ws + 50331648);     // 2 MiB
    float*  xdbl    = (float*)(ws + 52428800);      // 2 MiB   (dead after scan_p3)
    ushort* xdblh   = (ushort*)(ws + 54525952);     // 1 MiB
    ushort* delta_h = (ushort*)(ws + 55574528);     // 16 MiB  (dead after scan_p3)
    ushort* yb      = (ushort*)(ws + 72351744);     // 16 MiB
    ushort* hid_h   = (ushort*)(ws + 89128960);     // 8 MiB
    // 32 MiB multi-use region at 97517568 (time-disjoint)
    ushort* inp_h   = (ushort*)(ws + 97517568);
    float*  parts   = (float*)(ws + 97517568);
    float*  Hbuf    = (float*)(ws + 97517568);
    float*  sumdt   = (float*)(ws + 105906176);
    ushort* dtp_h   = (ushort*)(ws + 131072000);    // 1 MiB
    ushort* outp_h  = (ushort*)(ws + 132120576);    // 16 MiB

    const int M = BB * LL;  // 2048

    // 0) all f32 -> bf16 conversions + x_proj pad, one dispatch
    cvt_all<<<30208, 256, 0, stream>>>(
        (const float4*)hidden, (const float4*)in_proj, (const float4*)dt_proj_w,
        (const float4*)out_proj, (const float4*)x_proj,
        (us4*)hid_h, (us4*)inp_h, (us4*)dtp_h, (us4*)outp_h, (us4*)xpp);

    // 1) xz = hidden @ in_proj^T   (2048x8192 bf16) — 256^2 kernel (67 us)
    gemm_nt256<false, true><<<dim3(8192 / 256, M / 256), 512, 0, stream>>>(
        hid_h, DMODEL, inp_h, DMODEL, nullptr, xz_h, 8192, DMODEL);

    // 2) x_conv = silu(causal_conv(x) + conv_b)
    conv_silu_kernel<<<(M * DINNER) / 256, 256, 0, stream>>>(xz_h, conv_w, conv_b, xc);

    // 3) x_dbl = x_conv @ x_proj_pad^T, K split 16x256 -> partials -> reduce
    gemm_nt<0, true, false><<<dim3(XDBL_LD / 128, M / 128, 16), 256, 0, stream>>>(
        xc, DINNER, xpp, DINNER, parts, nullptr, XDBL_LD, DINNER / 16, nullptr);
    reduce_k<16, true><<<(M * XDBL_LD / 4 + 255) / 256, 256, 0, stream>>>(
        (const float4*)parts, (long)M * XDBL_LD / 4, M * XDBL_LD / 4,
        (float4*)xdbl, (us4*)xdblh);

    // 4) delta = softplus(dt_lo @ dt_proj_w^T + dt_proj_b)  (bf16)
    gemm_nt<1, false, true><<<dim3(DINNER / 128, M / 128), 256, 0, stream>>>(
        xdblh, XDBL_LD, dtp_h, DTRANK, nullptr, delta_h, DINNER, DTRANK, dt_proj_b);

    // 5) chunked selective scan + D-skip + silu(z) gating -> y (bf16)
    scan_p1<<<dim3(DINNER / 256, NCH, BB), 256, 0, stream>>>(
        delta_h, xc, xdbl, A_log, Hbuf, sumdt);
    scan_p2<<<(BB * DINNER * DSTATE) / 256, 256, 0, stream>>>(
        A_log, sumdt, Hbuf);
    scan_p3<<<dim3(DINNER / 256, NCH, BB), 256, 0, stream>>>(
        delta_h, xc, xdbl, xz_h, A_log, Dp, Hbuf, yb);

    // 6) out = y @ out_proj^T — 128^2 z=1, grid 256 wg, direct f32 write
    //    (no split-K partials, no reduce dispatch)
    gemm_nt128d<true, false><<<dim3(DMODEL / 128, M / 128), 256, 0, stream>>>(
        yb, DINNER, outp_h, DINNER, out, nullptr, DMODEL, DINNER);
}

// Round 8
// 456.678 us; speedup vs baseline: 1.1152x; 1.1152x over previous
//
#include <hip/hip_runtime.h>
#include <hip/hip_bf16.h>
#include <stdint.h>

// Problem constants
#define BB 2
#define LL 1024
#define DMODEL 2048
#define DINNER 4096
#define DSTATE 16
#define DTRANK 128
#define XDBL_LD 256   // x_proj rows padded 160 -> 256
#define CHUNK 64
#define NCH (LL / CHUNK)   // 16

typedef unsigned short ushort;
using short8 = __attribute__((ext_vector_type(8))) short;
using f32x4  = __attribute__((ext_vector_type(4))) float;
using us4    = __attribute__((ext_vector_type(4))) ushort;

__device__ __forceinline__ float bf2f(ushort u) {
    union { uint32_t i; float f; } v; v.i = ((uint32_t)u) << 16; return v.f;
}
__device__ __forceinline__ ushort f2bf(float f) {
    union { float f; uint32_t i; } v; v.f = f;
    uint32_t lsb = (v.i >> 16) & 1u;
    uint32_t r = v.i + 0x7FFFu + lsb;   // RNE
    return (ushort)(r >> 16);
}

// Async global->LDS, 16B per lane (lane-ordered, unpadded LDS dest).
__device__ __forceinline__ void glds16(const ushort* g, ushort* l) {
    __builtin_amdgcn_global_load_lds(
        (const __attribute__((address_space(1))) void*)g,
        (__attribute__((address_space(3))) void*)l,
        16, 0, 0);
}

// ---------------------------------------------------------------------------
// Fused f32->bf16 conversion of all weights/activations + x_proj zero-pad.
// ---------------------------------------------------------------------------
__global__ __launch_bounds__(256) void cvt_all(
    const float4* __restrict__ hidden, const float4* __restrict__ inproj,
    const float4* __restrict__ dtw, const float4* __restrict__ outp,
    const float4* __restrict__ xproj,
    us4* __restrict__ hid_h, us4* __restrict__ inp_h, us4* __restrict__ dtp_h,
    us4* __restrict__ outp_h, us4* __restrict__ xpp)
{
    long i = (long)blockIdx.x * 256 + threadIdx.x;
    const float4* src; us4* dst; long j;
    if (i < 1048576)      { src = hidden; dst = hid_h;  j = i; }
    else if (i < 5242880) { src = inproj; dst = inp_h;  j = i - 1048576; }
    else if (i < 5373952) { src = dtw;    dst = dtp_h;  j = i - 5242880; }
    else if (i < 7471104) { src = outp;   dst = outp_h; j = i - 5373952; }
    else {
        j = i - 7471104; dst = xpp;
        if (j >= 163840) { us4 z = {0, 0, 0, 0}; dst[j] = z; return; }
        src = xproj;
    }
    float4 v = src[j];
    us4 o; o.x = f2bf(v.x); o.y = f2bf(v.y); o.z = f2bf(v.z); o.w = f2bf(v.w);
    dst[j] = o;
}

// ---------------------------------------------------------------------------
// 256x256 NT GEMM (r4 best variant: T2 swizzle + setprio + B-frag dedup,
// one __syncthreads per K-tile). 67 us / 1024 TF on gemm1 — local optimum
// after 6 schedule experiments (counted-vmcnt, SBAR, BK32 all regressed).
// ---------------------------------------------------------------------------
template <bool WF, bool WH>
__global__ __launch_bounds__(512, 2) void gemm_nt256(
    const ushort* __restrict__ A, int lda,
    const ushort* __restrict__ Bm, int ldb,
    float* __restrict__ Cf, ushort* __restrict__ Ch, int ldc,
    int K)
{
    __shared__ __align__(16) ushort sA[2][256 * 64];   // 2 x 32 KB
    __shared__ __align__(16) ushort sB[2][256 * 64];   // 2 x 32 KB

    const int tid  = threadIdx.x;
    const int lane = tid & 63;
    const int wave = tid >> 6;          // 0..7
    const int wr   = wave >> 2;         // 0..1 (M half)
    const int wcol = wave & 3;          // 0..3 (N quarter)
    const int lrow = lane & 15;
    const int lg   = lane >> 4;         // 0..3
    const int s7   = lane & 7;
    const int kb0 = ((0 + lg) ^ s7) << 4;
    const int kb1 = ((4 + lg) ^ s7) << 4;

    const int NT = gridDim.x, MT = gridDim.y;
    int mt, nt;
    if ((NT & 7) == 0) {
        int lin   = blockIdx.y * NT + blockIdx.x;
        int strip = NT >> 3;
        int xcd   = lin & 7;
        int idx   = lin >> 3;
        nt = xcd * strip + (idx % strip);
        mt = idx / strip;
    } else { mt = blockIdx.y; nt = blockIdx.x; }
    const long m0 = (long)mt * 256;
    const long n0 = (long)nt * 256;

    const long zoff = (long)blockIdx.z;
    A  += zoff * (long)K;
    Bm += zoff * (long)K;
    const long Mrows = (long)MT * 256;
    if (WF) Cf += zoff * Mrows * (long)ldc;

    f32x4 acc[8][4] = {};

    const int sr   = tid >> 3;                       // 0..63
    const int scol = (((tid & 7) ^ (sr & 7)) << 3);  // element col 0..56
    const ushort* Ag = A  + (m0 + sr) * (long)lda + scol;
    const ushort* Bg = Bm + (n0 + sr) * (long)ldb + scol;

    const int NKT = K >> 6;

    {
        ushort* dA0 = &sA[0][0] + tid * 8;
        ushort* dB0 = &sB[0][0] + tid * 8;
        #pragma unroll
        for (int c = 0; c < 4; ++c) {
            glds16(Ag + (c * 64) * (long)lda, dA0 + c * 4096);
            glds16(Bg + (c * 64) * (long)ldb, dB0 + c * 4096);
        }
    }
    __syncthreads();

    const int arow0 = (wr * 128 + lrow) * 128;
    const int brow0 = (wcol * 64 + lrow) * 128;

    for (int kt = 0; kt < NKT; ++kt) {
        const int p = kt & 1;
        const char* sap = (const char*)&sA[p][0];
        const char* sbp = (const char*)&sB[p][0];
        ushort* dA = &sA[p ^ 1][0] + tid * 8;
        ushort* dB = &sB[p ^ 1][0] + tid * 8;
        const long kn = (long)(kt + 1) << 6;
        const bool pf = (kt + 1 < NKT);

        short8 bf[4][2];
        #pragma unroll
        for (int j = 0; j < 4; ++j) {
            const int bb = brow0 + (j * 16) * 128;
            bf[j][0] = *(const short8*)(sbp + bb + kb0);
            bf[j][1] = *(const short8*)(sbp + bb + kb1);
        }

        #pragma unroll
        for (int mh = 0; mh < 2; ++mh) {
            short8 af[4][2];
            #pragma unroll
            for (int i4 = 0; i4 < 4; ++i4) {
                const int ab = arow0 + (mh * 64 + i4 * 16) * 128;
                af[i4][0] = *(const short8*)(sap + ab + kb0);
                af[i4][1] = *(const short8*)(sap + ab + kb1);
            }
            if (pf) {
                if (mh == 0) {
                    #pragma unroll
                    for (int c = 0; c < 4; ++c)
                        glds16(Ag + (c * 64) * (long)lda + kn, dA + c * 4096);
                } else {
                    #pragma unroll
                    for (int c = 0; c < 4; ++c)
                        glds16(Bg + (c * 64) * (long)ldb + kn, dB + c * 4096);
                }
            }
            __builtin_amdgcn_s_setprio(1);
            #pragma unroll
            for (int ks = 0; ks < 2; ++ks)
                #pragma unroll
                for (int i4 = 0; i4 < 4; ++i4)
                    #pragma unroll
                    for (int j = 0; j < 4; ++j)
                        acc[mh * 4 + i4][j] =
                            __builtin_amdgcn_mfma_f32_16x16x32_bf16(
                                af[i4][ks], bf[j][ks],
                                acc[mh * 4 + i4][j], 0, 0, 0);
            __builtin_amdgcn_s_setprio(0);
        }
        __syncthreads();
    }

    const int r0 = (lane >> 4) * 4;
    const int c0 = lane & 15;
    #pragma unroll
    for (int i = 0; i < 8; ++i) {
        #pragma unroll
        for (int j = 0; j < 4; ++j) {
            const long col = n0 + wcol * 64 + j * 16 + c0;
            #pragma unroll
            for (int r = 0; r < 4; ++r) {
                const long row = m0 + wr * 128 + i * 16 + r0 + r;
                const float v = acc[i][j][r];
                const long idx = row * (long)ldc + col;
                if (WF) Cf[idx] = v;
                if (WH) Ch[idx] = f2bf(v);
            }
        }
    }
}

// ---------------------------------------------------------------------------
// NEW: dedicated delta GEMM (M=2048, N=4096, K=128 fixed).
// delta = softplus(xdblh[:, :128] @ dtp_h^T + bias), bf16 out.
// Single-shot: whole K staged once (A 128x128 = 32 KB + B 256x128 = 64 KB),
// ONE barrier, 4 k-steps x 16 MFMA/wave, epilogue. Grid (16,16) = 256 wg =
// 1/CU. 8 waves (2M x 4N), 64x64 per wave. No K-loop, no double-buffer —
// the old K-loop machine ran this shape at 60-125 us of pure overhead.
// Swizzle (256-B rows, 16 slots): slot' = slot ^ (row&7) -> 2-way (free).
// K-chain per acc = k ascending, one MFMA per 32-k: bit-identical to old.
// ---------------------------------------------------------------------------
__global__ __launch_bounds__(512, 2) void gemm_delta(
    const ushort* __restrict__ A,    // xdblh, LD 256, cols 0..127 used
    const ushort* __restrict__ Bm,   // dtp_h, LD 128
    ushort* __restrict__ Ch,         // delta_h, LD 4096
    const float* __restrict__ bias)
{
    __shared__ __align__(16) ushort sA[128 * 128];   // 32 KB
    __shared__ __align__(16) ushort sB[256 * 128];   // 64 KB

    const int tid  = threadIdx.x;
    const int lane = tid & 63;
    const int wave = tid >> 6;          // 0..7
    const int wr   = wave >> 2;         // 0..1 (M half, 64 rows)
    const int wcol = wave & 3;          // 0..3 (N quarter, 64 cols)
    const int lrow = lane & 15;
    const int lg   = lane >> 4;         // 0..3
    const int s7r  = lrow & 7;          // swizzle key = row&7 = lrow&7

    // XCD-aware tile swizzle (NT=16, bijective: 256 wg % 8 == 0)
    const int NT = gridDim.x;
    int mt, nt;
    {
        int lin   = blockIdx.y * NT + blockIdx.x;
        int strip = NT >> 3;
        int xcd   = lin & 7;
        int idx   = lin >> 3;
        nt = xcd * strip + (idx % strip);
        mt = idx / strip;
    }
    const long m0 = (long)mt * 128;
    const long n0 = (long)nt * 256;

    // Staging: 16B slot l: row = l>>4, slot_lds = l&15; content = global
    // (row, slot_lds ^ (row&7)). Thread t covers l = c*512 + t:
    // row = c*32 + (t>>4), slot_lds = t&15, key (row&7) = (t>>4)&7.
    const int srow = tid >> 4;                                // 0..31
    const int scol = (((tid & 15) ^ ((tid >> 4) & 7)) << 3);  // elem col
    const ushort* Ag = A  + (m0 + srow) * (long)XDBL_LD + scol;
    const ushort* Bg = Bm + (n0 + srow) * (long)DTRANK + scol;

    #pragma unroll
    for (int c = 0; c < 4; ++c)
        glds16(Ag + (c * 32) * (long)XDBL_LD, &sA[0] + c * 4096 + tid * 8);
    #pragma unroll
    for (int c = 0; c < 8; ++c)
        glds16(Bg + (c * 32) * (long)DTRANK, &sB[0] + c * 4096 + tid * 8);
    __syncthreads();   // vmcnt(0) drain + publish; LDS read-only after

    f32x4 acc[4][4] = {};
    const char* sap = (const char*)&sA[0];
    const char* sbp = (const char*)&sB[0];
    const int arow0 = (wr * 64 + lrow) * 256;    // byte base of A rows
    const int brow0 = (wcol * 64 + lrow) * 256;  // byte base of B rows

    #pragma unroll
    for (int ks = 0; ks < 4; ++ks) {
        const int kb = ((ks * 4 + lg) ^ s7r) << 4;   // swizzled slot byte
        short8 af[4], bf[4];
        #pragma unroll
        for (int i = 0; i < 4; ++i)
            af[i] = *(const short8*)(sap + arow0 + (i * 16) * 256 + kb);
        #pragma unroll
        for (int j = 0; j < 4; ++j)
            bf[j] = *(const short8*)(sbp + brow0 + (j * 16) * 256 + kb);
        #pragma unroll
        for (int i = 0; i < 4; ++i)
            #pragma unroll
            for (int j = 0; j < 4; ++j)
                acc[i][j] = __builtin_amdgcn_mfma_f32_16x16x32_bf16(
                    af[i], bf[j], acc[i][j], 0, 0, 0);
    }

    // Epilogue: bias + softplus (identical formula), bf16 store.
    const int r0 = (lane >> 4) * 4;
    const int c0 = lane & 15;
    #pragma unroll
    for (int i = 0; i < 4; ++i) {
        #pragma unroll
        for (int j = 0; j < 4; ++j) {
            const long col = n0 + wcol * 64 + j * 16 + c0;
            const float bv = bias[col];
            #pragma unroll
            for (int r = 0; r < 4; ++r) {
                const long row = m0 + wr * 64 + i * 16 + r0 + r;
                float v = acc[i][j][r] + bv;
                v = (v > 20.f) ? v : log1pf(__expf(v));  // softplus
                Ch[row * (long)DINNER + col] = f2bf(v);
            }
        }
    }
}

// ---------------------------------------------------------------------------
// NT GEMM: 128x128 tile, 2-phase (kept for gemm3: x_dbl).
// ---------------------------------------------------------------------------
template <int EPI, bool WF, bool WH>
__global__ __launch_bounds__(256) void gemm_nt(
    const ushort* __restrict__ A, int lda,
    const ushort* __restrict__ Bm, int ldb,
    float* __restrict__ Cf, ushort* __restrict__ Ch, int ldc,
    int K, const float* __restrict__ bias)
{
    __shared__ __align__(16) ushort sA[128 * 64];   // 16 KB
    __shared__ __align__(16) ushort sB[128 * 64];   // 16 KB

    const int tid  = threadIdx.x;
    const int lane = tid & 63;
    const int wave = tid >> 6;
    const int wr = wave >> 1, wc = wave & 1;

    const int NT = gridDim.x, MT = gridDim.y;
    int mt, nt;
    if ((NT & 7) == 0) {
        int lin   = blockIdx.y * NT + blockIdx.x;
        int strip = NT >> 3;
        int xcd   = lin & 7;
        int idx   = lin >> 3;
        nt = xcd * strip + (idx % strip);
        mt = idx / strip;
    } else { mt = blockIdx.y; nt = blockIdx.x; }
    const long m0 = (long)mt * 128;
    const long n0 = (long)nt * 128;

    const long zoff = (long)blockIdx.z;
    A  += zoff * (long)K;
    Bm += zoff * (long)K;
    const long Mrows = (long)MT * 128;
    if (WF) Cf += zoff * Mrows * (long)ldc;
    if (WH) Ch += zoff * Mrows * (long)ldc;

    f32x4 acc[4][4] = {};

    const int lrow = lane & 15;
    const int lko  = (lane >> 4) << 3;

    const int sr = tid >> 3;            // 0..31
    const int sc = (tid & 7) << 3;      // element col 0..56
    const ushort* Ag = A  + (m0 + sr) * (long)lda + sc;
    const ushort* Bg = Bm + (n0 + sr) * (long)ldb + sc;
    ushort* lA = sA + tid * 8;
    ushort* lB = sB + tid * 8;

    for (int k0 = 0; k0 < K; k0 += 64) {
        __syncthreads();
        #pragma unroll
        for (int c = 0; c < 4; ++c) {
            glds16(Ag + (c * 32) * (long)lda + k0, lA + c * 2048);
            glds16(Bg + (c * 32) * (long)ldb + k0, lB + c * 2048);
        }
        __syncthreads();

        #pragma unroll
        for (int ks = 0; ks < 2; ++ks) {
            short8 af[4], bf[4];
            #pragma unroll
            for (int i = 0; i < 4; ++i)
                af[i] = *(const short8*)&sA[(wr * 64 + i * 16 + lrow) * 64 + ks * 32 + lko];
            #pragma unroll
            for (int j = 0; j < 4; ++j)
                bf[j] = *(const short8*)&sB[(wc * 64 + j * 16 + lrow) * 64 + ks * 32 + lko];

            #pragma unroll
            for (int i = 0; i < 4; ++i)
                #pragma unroll
                for (int j = 0; j < 4; ++j)
                    acc[i][j] = __builtin_amdgcn_mfma_f32_16x16x32_bf16(
                        af[i], bf[j], acc[i][j], 0, 0, 0);
        }
    }

    const int r0 = (lane >> 4) * 4;
    const int c0 = lane & 15;
    #pragma unroll
    for (int i = 0; i < 4; ++i) {
        #pragma unroll
        for (int j = 0; j < 4; ++j) {
            long col = n0 + wc * 64 + j * 16 + c0;
            float bv = 0.f;
            if (EPI == 1) bv = bias[col];
            #pragma unroll
            for (int r = 0; r < 4; ++r) {
                long row = m0 + wr * 64 + i * 16 + r0 + r;
                float v = acc[i][j][r];
                if (EPI == 1) {
                    v += bv;
                    v = (v > 20.f) ? v : log1pf(__expf(v));  // softplus
                }
                long idx = row * (long)ldc + col;
                if (WF) Cf[idx] = v;
                if (WH) Ch[idx] = f2bf(v);
            }
        }
    }
}

// ---------------------------------------------------------------------------
// Sum NZ per-split partials; write f32 and optionally bf16.
// ---------------------------------------------------------------------------
template <int NZ, bool WH_>
__global__ __launch_bounds__(256) void reduce_k(
    const float4* __restrict__ parts, long stride4, int n4,
    float4* __restrict__ outF, us4* __restrict__ outH)
{
    int i = blockIdx.x * 256 + threadIdx.x;
    if (i >= n4) return;
    float4 s = parts[i];
    #pragma unroll
    for (int z = 1; z < NZ; ++z) {
        float4 v = parts[(long)z * stride4 + i];
        s.x += v.x; s.y += v.y; s.z += v.z; s.w += v.w;
    }
    if (outF) outF[i] = s;
    if (WH_) {
        us4 o; o.x = f2bf(s.x); o.y = f2bf(s.y); o.z = f2bf(s.z); o.w = f2bf(s.w);
        outH[i] = o;
    }
}

// ---------------------------------------------------------------------------
// Depthwise causal conv(4) + bias + SiLU.
// ---------------------------------------------------------------------------
__global__ __launch_bounds__(256) void conv_silu_kernel(
    const ushort* __restrict__ xz,
    const float* __restrict__ cw,
    const float* __restrict__ cb,
    ushort* __restrict__ xc)
{
    int gid = blockIdx.x * 256 + threadIdx.x;   // over 2048*4096
    int d  = gid & (DINNER - 1);
    int rl = gid >> 12;
    int l  = rl & (LL - 1);
    float acc = cb[d];
    #pragma unroll
    for (int j = 0; j < 4; ++j) {
        int li = l - 3 + j;
        if (li >= 0)
            acc += cw[d * 4 + j] * bf2f(xz[(long)(rl - 3 + j) * 8192 + d]);
    }
    float s = acc / (1.f + __expf(-acc));
    xc[gid] = f2bf(s);
}

// ---------------------------------------------------------------------------
// Chunked selective scan (3 phases).
// ---------------------------------------------------------------------------
__global__ __launch_bounds__(256) void scan_p1(
    const ushort* __restrict__ delta,
    const ushort* __restrict__ xc,
    const float*  __restrict__ xdbl,
    const float*  __restrict__ A_log,
    float* __restrict__ Hbuf,
    float* __restrict__ sumdt_buf)
{
    __shared__ float sB[CHUNK * 16];
    const int tid = threadIdx.x;
    const int k = blockIdx.y, b = blockIdx.z;
    const int d = blockIdx.x * 256 + tid;
    const int row0 = b * LL + k * CHUNK;

    #pragma unroll
    for (int i = 0; i < 4; ++i) {
        int idx = i * 256 + tid;                 // = t*16 + s
        sB[idx] = xdbl[(long)(row0 + (idx >> 4)) * XDBL_LD + DTRANK + (idx & 15)];
    }
    __syncthreads();

    float A[DSTATE];
    const float4* Ap = (const float4*)(A_log + d * DSTATE);
    #pragma unroll
    for (int i = 0; i < 4; ++i) {
        float4 v = Ap[i];
        A[i*4+0] = -__expf(v.x); A[i*4+1] = -__expf(v.y);
        A[i*4+2] = -__expf(v.z); A[i*4+3] = -__expf(v.w);
    }

    float H[DSTATE];
    #pragma unroll
    for (int s = 0; s < DSTATE; ++s) H[s] = 0.f;
    float sumdt = 0.f;

    for (int t = 0; t < CHUNK; ++t) {
        const long row = row0 + t;
        const float dt = bf2f(delta[row * DINNER + d]);
        const float xv = bf2f(xc[row * DINNER + d]);
        const float dx = dt * xv;
        sumdt += dt;
        #pragma unroll
        for (int s = 0; s < DSTATE; ++s) {
            float dA = __expf(dt * A[s]);
            H[s] = H[s] * dA + dx * sB[t * 16 + s];
        }
    }

    const long o = ((long)(b * NCH + k) * DINNER + d) * DSTATE;
    float4* Ho = (float4*)(Hbuf + o);
    #pragma unroll
    for (int i = 0; i < 4; ++i) {
        float4 v; v.x = H[i*4+0]; v.y = H[i*4+1]; v.z = H[i*4+2]; v.w = H[i*4+3];
        Ho[i] = v;
    }
    sumdt_buf[(b * NCH + k) * DINNER + d] = sumdt;
}

__global__ __launch_bounds__(256) void scan_p2(
    const float* __restrict__ A_log,
    const float* __restrict__ sumdt_buf,
    float* __restrict__ Hbuf)
{
    int gid = blockIdx.x * 256 + threadIdx.x;   // 131072 = 2*4096*16
    int b = gid >> 16;
    int rem = gid & 65535;
    int d = rem >> 4, s = rem & 15;
    float A = -__expf(A_log[d * DSTATE + s]);
    float h = 0.f;
    for (int k = 0; k < NCH; ++k) {
        long idx = ((long)(b * NCH + k) * DINNER + d) * DSTATE + s;
        float Hk = Hbuf[idx];
        float sd = sumdt_buf[(b * NCH + k) * DINNER + d];
        Hbuf[idx] = h;
        h = h * __expf(A * sd) + Hk;
    }
}

__global__ __launch_bounds__(256) void scan_p3(
    const ushort* __restrict__ delta,
    const ushort* __restrict__ xc,
    const float*  __restrict__ xdbl,
    const ushort* __restrict__ xz,
    const float*  __restrict__ A_log,
    const float*  __restrict__ Dp,
    const float*  __restrict__ hin,
    ushort* __restrict__ y)
{
    __shared__ float sBC[CHUNK * 32];
    const int tid = threadIdx.x;
    const int k = blockIdx.y, b = blockIdx.z;
    const int d = blockIdx.x * 256 + tid;
    const int row0 = b * LL + k * CHUNK;

    #pragma unroll
    for (int i = 0; i < 8; ++i) {
        int idx = i * 256 + tid;                 // = t*32 + c
        sBC[idx] = xdbl[(long)(row0 + (idx >> 5)) * XDBL_LD + DTRANK + (idx & 31)];
    }
    __syncthreads();

    float A[DSTATE];
    const float4* Ap = (const float4*)(A_log + d * DSTATE);
    #pragma unroll
    for (int i = 0; i < 4; ++i) {
        float4 v = Ap[i];
        A[i*4+0] = -__expf(v.x); A[i*4+1] = -__expf(v.y);
        A[i*4+2] = -__expf(v.z); A[i*4+3] = -__expf(v.w);
    }
    const float Dd = Dp[d];

    float h[DSTATE];
    const float4* Hp = (const float4*)(hin + ((long)(b * NCH + k) * DINNER + d) * DSTATE);
    #pragma unroll
    for (int i = 0; i < 4; ++i) {
        float4 v = Hp[i];
        h[i*4+0] = v.x; h[i*4+1] = v.y; h[i*4+2] = v.z; h[i*4+3] = v.w;
    }

    for (int t = 0; t < CHUNK; ++t) {
        const long row = row0 + t;
        const float dt = bf2f(delta[row * DINNER + d]);
        const float xv = bf2f(xc[row * DINNER + d]);
        const float dx = dt * xv;
        float yt = 0.f;
        #pragma unroll
        for (int s = 0; s < DSTATE; ++s) {
            float dA = __expf(dt * A[s]);
            h[s] = h[s] * dA + dx * sBC[t * 32 + s];
            yt += h[s] * sBC[t * 32 + 16 + s];
        }
        yt += xv * Dd;
        const float zv = bf2f(xz[row * 8192 + DINNER + d]);
        yt *= zv / (1.f + __expf(-zv));
        y[row * DINNER + d] = f2bf(yt);
    }
}

// ---------------------------------------------------------------------------
extern "C" void kernel_launch(void* const* d_in, const int* in_sizes, int n_in,
                              void* d_out, int out_size, void* d_ws, size_t ws_size,
                              hipStream_t stream)
{
    const float* hidden    = (const float*)d_in[0];
    const float* in_proj   = (const float*)d_in[1];
    const float* conv_w    = (const float*)d_in[2];
    const float* conv_b    = (const float*)d_in[3];
    const float* x_proj    = (const float*)d_in[4];
    const float* dt_proj_w = (const float*)d_in[5];
    const float* dt_proj_b = (const float*)d_in[6];
    const float* A_log     = (const float*)d_in[7];
    const float* Dp        = (const float*)d_in[8];
    const float* out_proj  = (const float*)d_in[9];
    float* out = (float*)d_out;

    // Workspace layout (bytes, all 16B aligned)
    char* ws = (char*)d_ws;
    ushort* xz_h    = (ushort*)(ws);                // 32 MiB  (dead after scan_p3)
    ushort* xc      = (ushort*)(ws + 33554432);     // 16 MiB  (dead after scan_p3)
    ushort* xpp     = (ushort*)(ws + 50331648);     // 2 MiB
    float*  xdbl    = (float*)(ws + 52428800);      // 2 MiB   (dead after scan_p3)
    ushort* xdblh   = (ushort*)(ws + 54525952);     // 1 MiB
    ushort* delta_h = (ushort*)(ws + 55574528);     // 16 MiB  (dead after scan_p3)
    ushort* yb      = (ushort*)(ws + 72351744);     // 16 MiB
    ushort* hid_h   = (ushort*)(ws + 89128960);     // 8 MiB
    // 32 MiB multi-use region at 97517568 (time-disjoint)
    ushort* inp_h   = (ushort*)(ws + 97517568);
    float*  parts   = (float*)(ws + 97517568);
    float*  Hbuf    = (float*)(ws + 97517568);
    float*  sumdt   = (float*)(ws + 105906176);
    ushort* dtp_h   = (ushort*)(ws + 131072000);    // 1 MiB
    ushort* outp_h  = (ushort*)(ws + 132120576);    // 16 MiB
    float*  parts2  = (float*)(ws);                 // 4 x 16 MiB, aliases dead bufs

    const int M = BB * LL;  // 2048

    // 0) all f32 -> bf16 conversions + x_proj pad, one dispatch
    cvt_all<<<30208, 256, 0, stream>>>(
        (const float4*)hidden, (const float4*)in_proj, (const float4*)dt_proj_w,
        (const float4*)out_proj, (const float4*)x_proj,
        (us4*)hid_h, (us4*)inp_h, (us4*)dtp_h, (us4*)outp_h, (us4*)xpp);

    // 1) xz = hidden @ in_proj^T   (2048x8192 bf16) — 256^2 kernel (67 us)
    gemm_nt256<false, true><<<dim3(8192 / 256, M / 256), 512, 0, stream>>>(
        hid_h, DMODEL, inp_h, DMODEL, nullptr, xz_h, 8192, DMODEL);

    // 2) x_conv = silu(causal_conv(x) + conv_b)
    conv_silu_kernel<<<(M * DINNER) / 256, 256, 0, stream>>>(xz_h, conv_w, conv_b, xc);

    // 3) x_dbl = x_conv @ x_proj_pad^T, K split 16x256 -> partials -> reduce
    gemm_nt<0, true, false><<<dim3(XDBL_LD / 128, M / 128, 16), 256, 0, stream>>>(
        xc, DINNER, xpp, DINNER, parts, nullptr, XDBL_LD, DINNER / 16, nullptr);
    reduce_k<16, true><<<(M * XDBL_LD / 4 + 255) / 256, 256, 0, stream>>>(
        (const float4*)parts, (long)M * XDBL_LD / 4, M * XDBL_LD / 4,
        (float4*)xdbl, (us4*)xdblh);

    // 4) delta = softplus(dt_lo @ dt_proj_w^T + dt_proj_b) — dedicated
    //    single-shot kernel (whole K=128 staged once, 1 barrier)
    gemm_delta<<<dim3(DINNER / 256, M / 128), 512, 0, stream>>>(
        xdblh, dtp_h, delta_h, dt_proj_b);

    // 5) chunked selective scan + D-skip + silu(z) gating -> y (bf16)
    scan_p1<<<dim3(DINNER / 256, NCH, BB), 256, 0, stream>>>(
        delta_h, xc, xdbl, A_log, Hbuf, sumdt);
    scan_p2<<<(BB * DINNER * DSTATE) / 256, 256, 0, stream>>>(
        A_log, sumdt, Hbuf);
    scan_p3<<<dim3(DINNER / 256, NCH, BB), 256, 0, stream>>>(
        delta_h, xc, xdbl, xz_h, A_log, Dp, Hbuf, yb);

    // 6) out = y @ out_proj^T, K split 4x1024 -> partials -> reduce
    //    (R1-measured path restored for single-variable attribution)
    gemm_nt256<true, false><<<dim3(DMODEL / 256, M / 256, 4), 512, 0, stream>>>(
        yb, DINNER, outp_h, DINNER, parts2, nullptr, DMODEL, DINNER / 4);
    reduce_k<4, false><<<(M * DMODEL / 4 + 255) / 256, 256, 0, stream>>>(
        (const float4*)parts2, (long)M * DMODEL / 4, M * DMODEL / 4,
        (float4*)out, nullptr);
}

// Round 9
// 453.655 us; speedup vs baseline: 1.1226x; 1.0067x over previous
//
#include <hip/hip_runtime.h>
#include <hip/hip_bf16.h>
#include <stdint.h>

// Problem constants
#define BB 2
#define LL 1024
#define DMODEL 2048
#define DINNER 4096
#define DSTATE 16
#define DTRANK 128
#define XDBL_LD 256   // x_proj rows padded 160 -> 256
#define CHUNK 64
#define NCH (LL / CHUNK)   // 16

typedef unsigned short ushort;
using short8 = __attribute__((ext_vector_type(8))) short;
using f32x4  = __attribute__((ext_vector_type(4))) float;
using us4    = __attribute__((ext_vector_type(4))) ushort;

__device__ __forceinline__ float bf2f(ushort u) {
    union { uint32_t i; float f; } v; v.i = ((uint32_t)u) << 16; return v.f;
}
__device__ __forceinline__ ushort f2bf(float f) {
    union { float f; uint32_t i; } v; v.f = f;
    uint32_t lsb = (v.i >> 16) & 1u;
    uint32_t r = v.i + 0x7FFFu + lsb;   // RNE
    return (ushort)(r >> 16);
}

// Async global->LDS, 16B per lane (lane-ordered, unpadded LDS dest).
__device__ __forceinline__ void glds16(const ushort* g, ushort* l) {
    __builtin_amdgcn_global_load_lds(
        (const __attribute__((address_space(1))) void*)g,
        (__attribute__((address_space(3))) void*)l,
        16, 0, 0);
}

#define BAR()  __builtin_amdgcn_s_barrier()
#define WAITV(n) asm volatile("s_waitcnt vmcnt(" #n ")" ::: "memory")
#define LGKM0() do { asm volatile("s_waitcnt lgkmcnt(0)" ::: "memory"); \
                     __builtin_amdgcn_sched_barrier(0); } while (0)

// ---------------------------------------------------------------------------
// Fused f32->bf16 conversion of all weights/activations + x_proj zero-pad.
// ---------------------------------------------------------------------------
__global__ __launch_bounds__(256) void cvt_all(
    const float4* __restrict__ hidden, const float4* __restrict__ inproj,
    const float4* __restrict__ dtw, const float4* __restrict__ outp,
    const float4* __restrict__ xproj,
    us4* __restrict__ hid_h, us4* __restrict__ inp_h, us4* __restrict__ dtp_h,
    us4* __restrict__ outp_h, us4* __restrict__ xpp)
{
    long i = (long)blockIdx.x * 256 + threadIdx.x;
    const float4* src; us4* dst; long j;
    if (i < 1048576)      { src = hidden; dst = hid_h;  j = i; }
    else if (i < 5242880) { src = inproj; dst = inp_h;  j = i - 1048576; }
    else if (i < 5373952) { src = dtw;    dst = dtp_h;  j = i - 5242880; }
    else if (i < 7471104) { src = outp;   dst = outp_h; j = i - 5373952; }
    else {
        j = i - 7471104; dst = xpp;
        if (j >= 163840) { us4 z = {0, 0, 0, 0}; dst[j] = z; return; }
        src = xproj;
    }
    float4 v = src[j];
    us4 o; o.x = f2bf(v.x); o.y = f2bf(v.y); o.z = f2bf(v.z); o.w = f2bf(v.w);
    dst[j] = o;
}

// ---------------------------------------------------------------------------
// 256x256 NT GEMM — m201-topology phase loop.
// 512 thr = 8 waves (2M x 4N), BK=64, dbuf 128 KiB, T2 swizzle.
// Per K-tile: 4 phases, ONE s_barrier each, reads BEFORE the barrier,
// lgkmcnt(0) after it, 16 MFMA; next phase's reads follow the MFMA with no
// intervening barrier -> fast waves' reads overlap slow waves' MFMA.
// Counted vmcnt(4) before the barriers of P0/P1/P3 (derivation in session
// notes; tail drains 2->0). Stage order per tile: SA0,SB0,SB1,SA1 (2 glds16
// each), B-region permutation identical to the r3 harness-verified kernel.
// Accumulation chains unchanged -> bit-identical output. K%64==0.
// ---------------------------------------------------------------------------
template <bool WF, bool WH>
__global__ __launch_bounds__(512, 2) void gemm_nt256(
    const ushort* __restrict__ A, int lda,
    const ushort* __restrict__ Bm, int ldb,
    float* __restrict__ Cf, ushort* __restrict__ Ch, int ldc,
    int K)
{
    __shared__ __align__(16) ushort sA[2][256 * 64];   // 2 x 32 KB
    __shared__ __align__(16) ushort sB[2][256 * 64];   // 2 x 32 KB

    const int tid  = threadIdx.x;
    const int lane = tid & 63;
    const int wave = tid >> 6;          // 0..7
    const int wr   = wave >> 2;         // 0..1 (M half)
    const int wcol = wave & 3;          // 0..3 (N quarter)
    const int lrow = lane & 15;
    const int lg   = lane >> 4;         // 0..3
    const int s7   = lane & 7;
    const int kb0 = ((0 + lg) ^ s7) << 4;
    const int kb1 = ((4 + lg) ^ s7) << 4;

    const int NT = gridDim.x, MT = gridDim.y;
    int mt, nt;
    if ((NT & 7) == 0) {
        int lin   = blockIdx.y * NT + blockIdx.x;
        int strip = NT >> 3;
        int xcd   = lin & 7;
        int idx   = lin >> 3;
        nt = xcd * strip + (idx % strip);
        mt = idx / strip;
    } else { mt = blockIdx.y; nt = blockIdx.x; }
    const long m0 = (long)mt * 256;
    const long n0 = (long)nt * 256;

    const long zoff = (long)blockIdx.z;
    A  += zoff * (long)K;
    Bm += zoff * (long)K;
    const long Mrows = (long)MT * 256;
    if (WF) Cf += zoff * Mrows * (long)ldc;

    f32x4 acc[8][4] = {};

    // staging geometry (A linear row-major; B region-permuted, r3-verified)
    const int sr   = tid >> 3;                       // 0..63
    const int scol = (((tid & 7) ^ (sr & 7)) << 3);  // element col 0..56
    const ushort* Ag = A + (m0 + sr) * (long)lda + scol;
    const int brow_s = ((sr >> 5) << 6) + (sr & 31);
    const ushort* BgS = Bm + (n0 + brow_s) * (long)ldb + scol;

    const int NKT = K >> 6;

    // A-read base (A LDS plain row-major [256][64])
    const int arow0 = (wr * 128 + lrow) * 128;            // bytes
    // B-read base: region (wcol>>1), row-in-region 32*(wcol&1)+lrow
    const int brow0 = (wcol >> 1) * 8192 + (((wcol & 1) << 5) + lrow) * 128;

    auto stageA = [&](int h, ushort* dst, long koff) {
        glds16(Ag + (h * 64) * (long)lda + koff,        dst + h * 4096 + tid * 8);
        glds16(Ag + (h * 64 + 128) * (long)lda + koff,  dst + (h + 2) * 4096 + tid * 8);
    };
    auto stageB = [&](int h, ushort* dst, long koff) {
        glds16(BgS + (32 * h) * (long)ldb + koff,       dst + (2 * h) * 4096 + tid * 8);
        glds16(BgS + (128 + 32 * h) * (long)ldb + koff, dst + (2 * h + 1) * 4096 + tid * 8);
    };

    short8 af[4][2], bf0[2][2], bf1[2][2];

    auto readA = [&](const char* sap, int mh) {
        #pragma unroll
        for (int i4 = 0; i4 < 4; ++i4) {
            const int ab = arow0 + (mh * 64 + i4 * 16) * 128;
            af[i4][0] = *(const short8*)(sap + ab + kb0);
            af[i4][1] = *(const short8*)(sap + ab + kb1);
        }
    };
    auto readB = [&](const char* sbp, int nh, short8 (*bfr)[2]) {
        const int bb = brow0 + nh * 16384;
        #pragma unroll
        for (int j2 = 0; j2 < 2; ++j2) {
            bfr[j2][0] = *(const short8*)(sbp + bb + j2 * (16 * 128) + kb0);
            bfr[j2][1] = *(const short8*)(sbp + bb + j2 * (16 * 128) + kb1);
        }
    };
    auto mfma16 = [&](int mh, int nh, short8 (*bfr)[2]) {
        __builtin_amdgcn_s_setprio(1);
        #pragma unroll
        for (int ks = 0; ks < 2; ++ks)
            #pragma unroll
            for (int i4 = 0; i4 < 4; ++i4)
                #pragma unroll
                for (int j2 = 0; j2 < 2; ++j2)
                    acc[mh * 4 + i4][nh * 2 + j2] =
                        __builtin_amdgcn_mfma_f32_16x16x32_bf16(
                            af[i4][ks], bfr[j2][ks],
                            acc[mh * 4 + i4][nh * 2 + j2], 0, 0, 0);
        __builtin_amdgcn_s_setprio(0);
    };

    // Prologue: stage tile 0 (order SA0,SB0,SB1,SA1); publish SA0+SB0.
    stageA(0, &sA[0][0], 0);
    stageB(0, &sB[0][0], 0);
    stageB(1, &sB[0][0], 0);
    stageA(1, &sA[0][0], 0);
    WAITV(4);
    BAR();

    for (int kt = 0; kt < NKT; ++kt) {
        const char* sap = (const char*)&sA[kt & 1][0];
        const char* sbp = (const char*)&sB[kt & 1][0];
        ushort* dA = &sA[(kt & 1) ^ 1][0];
        ushort* dB = &sB[(kt & 1) ^ 1][0];
        const long kn = (long)(kt + 1) << 6;
        const bool pf = (kt + 1 < NKT);

        // ---- P0 (mh0, nh0): reads A0 + B0; stage SA0(next)
        readA(sap, 0);
        readB(sbp, 0, bf0);
        if (pf) { stageA(0, dA, kn); WAITV(4); } else { WAITV(2); }
        BAR(); LGKM0();
        mfma16(0, 0, bf0);

        // ---- P1 (mh0, nh1): reads B1; stage SB0(next)
        readB(sbp, 1, bf1);
        if (pf) { stageB(0, dB, kn); WAITV(4); } else { WAITV(0); }
        BAR(); LGKM0();
        mfma16(0, 1, bf1);

        // ---- P2 (mh1, nh0): reads A1 (B0 held); stage SB1(next)
        readA(sap, 1);
        if (pf) stageB(1, dB, kn);
        BAR(); LGKM0();
        mfma16(1, 0, bf0);

        // ---- P3 (mh1, nh1): no reads (A1,B1 held); stage SA1(next)
        if (pf) { stageA(1, dA, kn); WAITV(4); }
        BAR(); LGKM0();
        mfma16(1, 1, bf1);
    }

    // C/D mapping: col = lane&15, row = (lane>>4)*4 + reg (verified layout).
    const int r0 = (lane >> 4) * 4;
    const int c0 = lane & 15;
    #pragma unroll
    for (int i = 0; i < 8; ++i) {
        #pragma unroll
        for (int j = 0; j < 4; ++j) {
            const long col = n0 + wcol * 64 + j * 16 + c0;
            #pragma unroll
            for (int r = 0; r < 4; ++r) {
                const long row = m0 + wr * 128 + i * 16 + r0 + r;
                const float v = acc[i][j][r];
                const long idx = row * (long)ldc + col;
                if (WF) Cf[idx] = v;
                if (WH) Ch[idx] = f2bf(v);
            }
        }
    }
}

// ---------------------------------------------------------------------------
// Dedicated delta GEMM (M=2048, N=4096, K=128 fixed).
// delta = softplus(xdblh[:, :128] @ dtp_h^T + bias), bf16 out.
// Whole K staged once (A 32 KB + B 64 KB), ONE barrier, 4 k-steps x 16 MFMA.
// ---------------------------------------------------------------------------
__global__ __launch_bounds__(512, 2) void gemm_delta(
    const ushort* __restrict__ A,    // xdblh, LD 256, cols 0..127 used
    const ushort* __restrict__ Bm,   // dtp_h, LD 128
    ushort* __restrict__ Ch,         // delta_h, LD 4096
    const float* __restrict__ bias)
{
    __shared__ __align__(16) ushort sA[128 * 128];   // 32 KB
    __shared__ __align__(16) ushort sB[256 * 128];   // 64 KB

    const int tid  = threadIdx.x;
    const int lane = tid & 63;
    const int wave = tid >> 6;          // 0..7
    const int wr   = wave >> 2;         // 0..1 (M half, 64 rows)
    const int wcol = wave & 3;          // 0..3 (N quarter, 64 cols)
    const int lrow = lane & 15;
    const int lg   = lane >> 4;         // 0..3
    const int s7r  = lrow & 7;          // swizzle key = row&7 = lrow&7

    const int NT = gridDim.x;
    int mt, nt;
    {
        int lin   = blockIdx.y * NT + blockIdx.x;
        int strip = NT >> 3;
        int xcd   = lin & 7;
        int idx   = lin >> 3;
        nt = xcd * strip + (idx % strip);
        mt = idx / strip;
    }
    const long m0 = (long)mt * 128;
    const long n0 = (long)nt * 256;

    const int srow = tid >> 4;                                // 0..31
    const int scol = (((tid & 15) ^ ((tid >> 4) & 7)) << 3);  // elem col
    const ushort* Ag = A  + (m0 + srow) * (long)XDBL_LD + scol;
    const ushort* Bg = Bm + (n0 + srow) * (long)DTRANK + scol;

    #pragma unroll
    for (int c = 0; c < 4; ++c)
        glds16(Ag + (c * 32) * (long)XDBL_LD, &sA[0] + c * 4096 + tid * 8);
    #pragma unroll
    for (int c = 0; c < 8; ++c)
        glds16(Bg + (c * 32) * (long)DTRANK, &sB[0] + c * 4096 + tid * 8);
    __syncthreads();   // vmcnt(0) drain + publish; LDS read-only after

    f32x4 acc[4][4] = {};
    const char* sap = (const char*)&sA[0];
    const char* sbp = (const char*)&sB[0];
    const int arow0 = (wr * 64 + lrow) * 256;    // byte base of A rows
    const int brow0 = (wcol * 64 + lrow) * 256;  // byte base of B rows

    #pragma unroll
    for (int ks = 0; ks < 4; ++ks) {
        const int kb = ((ks * 4 + lg) ^ s7r) << 4;   // swizzled slot byte
        short8 af[4], bf[4];
        #pragma unroll
        for (int i = 0; i < 4; ++i)
            af[i] = *(const short8*)(sap + arow0 + (i * 16) * 256 + kb);
        #pragma unroll
        for (int j = 0; j < 4; ++j)
            bf[j] = *(const short8*)(sbp + brow0 + (j * 16) * 256 + kb);
        #pragma unroll
        for (int i = 0; i < 4; ++i)
            #pragma unroll
            for (int j = 0; j < 4; ++j)
                acc[i][j] = __builtin_amdgcn_mfma_f32_16x16x32_bf16(
                    af[i], bf[j], acc[i][j], 0, 0, 0);
    }

    const int r0 = (lane >> 4) * 4;
    const int c0 = lane & 15;
    #pragma unroll
    for (int i = 0; i < 4; ++i) {
        #pragma unroll
        for (int j = 0; j < 4; ++j) {
            const long col = n0 + wcol * 64 + j * 16 + c0;
            const float bv = bias[col];
            #pragma unroll
            for (int r = 0; r < 4; ++r) {
                const long row = m0 + wr * 64 + i * 16 + r0 + r;
                float v = acc[i][j][r] + bv;
                v = (v > 20.f) ? v : log1pf(__expf(v));  // softplus
                Ch[row * (long)DINNER + col] = f2bf(v);
            }
        }
    }
}

// ---------------------------------------------------------------------------
// NT GEMM: 128x128 tile, 2-phase (kept for gemm3: x_dbl).
// ---------------------------------------------------------------------------
template <int EPI, bool WF, bool WH>
__global__ __launch_bounds__(256) void gemm_nt(
    const ushort* __restrict__ A, int lda,
    const ushort* __restrict__ Bm, int ldb,
    float* __restrict__ Cf, ushort* __restrict__ Ch, int ldc,
    int K, const float* __restrict__ bias)
{
    __shared__ __align__(16) ushort sA[128 * 64];   // 16 KB
    __shared__ __align__(16) ushort sB[128 * 64];   // 16 KB

    const int tid  = threadIdx.x;
    const int lane = tid & 63;
    const int wave = tid >> 6;
    const int wr = wave >> 1, wc = wave & 1;

    const int NT = gridDim.x, MT = gridDim.y;
    int mt, nt;
    if ((NT & 7) == 0) {
        int lin   = blockIdx.y * NT + blockIdx.x;
        int strip = NT >> 3;
        int xcd   = lin & 7;
        int idx   = lin >> 3;
        nt = xcd * strip + (idx % strip);
        mt = idx / strip;
    } else { mt = blockIdx.y; nt = blockIdx.x; }
    const long m0 = (long)mt * 128;
    const long n0 = (long)nt * 128;

    const long zoff = (long)blockIdx.z;
    A  += zoff * (long)K;
    Bm += zoff * (long)K;
    const long Mrows = (long)MT * 128;
    if (WF) Cf += zoff * Mrows * (long)ldc;
    if (WH) Ch += zoff * Mrows * (long)ldc;

    f32x4 acc[4][4] = {};

    const int lrow = lane & 15;
    const int lko  = (lane >> 4) << 3;

    const int sr = tid >> 3;            // 0..31
    const int sc = (tid & 7) << 3;      // element col 0..56
    const ushort* Ag = A  + (m0 + sr) * (long)lda + sc;
    const ushort* Bg = Bm + (n0 + sr) * (long)ldb + sc;
    ushort* lA = sA + tid * 8;
    ushort* lB = sB + tid * 8;

    for (int k0 = 0; k0 < K; k0 += 64) {
        __syncthreads();
        #pragma unroll
        for (int c = 0; c < 4; ++c) {
            glds16(Ag + (c * 32) * (long)lda + k0, lA + c * 2048);
            glds16(Bg + (c * 32) * (long)ldb + k0, lB + c * 2048);
        }
        __syncthreads();

        #pragma unroll
        for (int ks = 0; ks < 2; ++ks) {
            short8 af[4], bf[4];
            #pragma unroll
            for (int i = 0; i < 4; ++i)
                af[i] = *(const short8*)&sA[(wr * 64 + i * 16 + lrow) * 64 + ks * 32 + lko];
            #pragma unroll
            for (int j = 0; j < 4; ++j)
                bf[j] = *(const short8*)&sB[(wc * 64 + j * 16 + lrow) * 64 + ks * 32 + lko];

            #pragma unroll
            for (int i = 0; i < 4; ++i)
                #pragma unroll
                for (int j = 0; j < 4; ++j)
                    acc[i][j] = __builtin_amdgcn_mfma_f32_16x16x32_bf16(
                        af[i], bf[j], acc[i][j], 0, 0, 0);
        }
    }

    const int r0 = (lane >> 4) * 4;
    const int c0 = lane & 15;
    #pragma unroll
    for (int i = 0; i < 4; ++i) {
        #pragma unroll
        for (int j = 0; j < 4; ++j) {
            long col = n0 + wc * 64 + j * 16 + c0;
            float bv = 0.f;
            if (EPI == 1) bv = bias[col];
            #pragma unroll
            for (int r = 0; r < 4; ++r) {
                long row = m0 + wr * 64 + i * 16 + r0 + r;
                float v = acc[i][j][r];
                if (EPI == 1) {
                    v += bv;
                    v = (v > 20.f) ? v : log1pf(__expf(v));  // softplus
                }
                long idx = row * (long)ldc + col;
                if (WF) Cf[idx] = v;
                if (WH) Ch[idx] = f2bf(v);
            }
        }
    }
}

// ---------------------------------------------------------------------------
// Sum NZ per-split partials; write f32 and optionally bf16.
// ---------------------------------------------------------------------------
template <int NZ, bool WH_>
__global__ __launch_bounds__(256) void reduce_k(
    const float4* __restrict__ parts, long stride4, int n4,
    float4* __restrict__ outF, us4* __restrict__ outH)
{
    int i = blockIdx.x * 256 + threadIdx.x;
    if (i >= n4) return;
    float4 s = parts[i];
    #pragma unroll
    for (int z = 1; z < NZ; ++z) {
        float4 v = parts[(long)z * stride4 + i];
        s.x += v.x; s.y += v.y; s.z += v.z; s.w += v.w;
    }
    if (outF) outF[i] = s;
    if (WH_) {
        us4 o; o.x = f2bf(s.x); o.y = f2bf(s.y); o.z = f2bf(s.z); o.w = f2bf(s.w);
        outH[i] = o;
    }
}

// ---------------------------------------------------------------------------
// Depthwise causal conv(4) + bias + SiLU.
// ---------------------------------------------------------------------------
__global__ __launch_bounds__(256) void conv_silu_kernel(
    const ushort* __restrict__ xz,
    const float* __restrict__ cw,
    const float* __restrict__ cb,
    ushort* __restrict__ xc)
{
    int gid = blockIdx.x * 256 + threadIdx.x;   // over 2048*4096
    int d  = gid & (DINNER - 1);
    int rl = gid >> 12;
    int l  = rl & (LL - 1);
    float acc = cb[d];
    #pragma unroll
    for (int j = 0; j < 4; ++j) {
        int li = l - 3 + j;
        if (li >= 0)
            acc += cw[d * 4 + j] * bf2f(xz[(long)(rl - 3 + j) * 8192 + d]);
    }
    float s = acc / (1.f + __expf(-acc));
    xc[gid] = f2bf(s);
}

// ---------------------------------------------------------------------------
// Chunked selective scan (3 phases).
// ---------------------------------------------------------------------------
__global__ __launch_bounds__(256) void scan_p1(
    const ushort* __restrict__ delta,
    const ushort* __restrict__ xc,
    const float*  __restrict__ xdbl,
    const float*  __restrict__ A_log,
    float* __restrict__ Hbuf,
    float* __restrict__ sumdt_buf)
{
    __shared__ float sB[CHUNK * 16];
    const int tid = threadIdx.x;
    const int k = blockIdx.y, b = blockIdx.z;
    const int d = blockIdx.x * 256 + tid;
    const int row0 = b * LL + k * CHUNK;

    #pragma unroll
    for (int i = 0; i < 4; ++i) {
        int idx = i * 256 + tid;                 // = t*16 + s
        sB[idx] = xdbl[(long)(row0 + (idx >> 4)) * XDBL_LD + DTRANK + (idx & 15)];
    }
    __syncthreads();

    float A[DSTATE];
    const float4* Ap = (const float4*)(A_log + d * DSTATE);
    #pragma unroll
    for (int i = 0; i < 4; ++i) {
        float4 v = Ap[i];
        A[i*4+0] = -__expf(v.x); A[i*4+1] = -__expf(v.y);
        A[i*4+2] = -__expf(v.z); A[i*4+3] = -__expf(v.w);
    }

    float H[DSTATE];
    #pragma unroll
    for (int s = 0; s < DSTATE; ++s) H[s] = 0.f;
    float sumdt = 0.f;

    for (int t = 0; t < CHUNK; ++t) {
        const long row = row0 + t;
        const float dt = bf2f(delta[row * DINNER + d]);
        const float xv = bf2f(xc[row * DINNER + d]);
        const float dx = dt * xv;
        sumdt += dt;
        #pragma unroll
        for (int s = 0; s < DSTATE; ++s) {
            float dA = __expf(dt * A[s]);
            H[s] = H[s] * dA + dx * sB[t * 16 + s];
        }
    }

    const long o = ((long)(b * NCH + k) * DINNER + d) * DSTATE;
    float4* Ho = (float4*)(Hbuf + o);
    #pragma unroll
    for (int i = 0; i < 4; ++i) {
        float4 v; v.x = H[i*4+0]; v.y = H[i*4+1]; v.z = H[i*4+2]; v.w = H[i*4+3];
        Ho[i] = v;
    }
    sumdt_buf[(b * NCH + k) * DINNER + d] = sumdt;
}

__global__ __launch_bounds__(256) void scan_p2(
    const float* __restrict__ A_log,
    const float* __restrict__ sumdt_buf,
    float* __restrict__ Hbuf)
{
    int gid = blockIdx.x * 256 + threadIdx.x;   // 131072 = 2*4096*16
    int b = gid >> 16;
    int rem = gid & 65535;
    int d = rem >> 4, s = rem & 15;
    float A = -__expf(A_log[d * DSTATE + s]);
    float h = 0.f;
    for (int k = 0; k < NCH; ++k) {
        long idx = ((long)(b * NCH + k) * DINNER + d) * DSTATE + s;
        float Hk = Hbuf[idx];
        float sd = sumdt_buf[(b * NCH + k) * DINNER + d];
        Hbuf[idx] = h;
        h = h * __expf(A * sd) + Hk;
    }
}

__global__ __launch_bounds__(256) void scan_p3(
    const ushort* __restrict__ delta,
    const ushort* __restrict__ xc,
    const float*  __restrict__ xdbl,
    const ushort* __restrict__ xz,
    const float*  __restrict__ A_log,
    const float*  __restrict__ Dp,
    const float*  __restrict__ hin,
    ushort* __restrict__ y)
{
    __shared__ float sBC[CHUNK * 32];
    const int tid = threadIdx.x;
    const int k = blockIdx.y, b = blockIdx.z;
    const int d = blockIdx.x * 256 + tid;
    const int row0 = b * LL + k * CHUNK;

    #pragma unroll
    for (int i = 0; i < 8; ++i) {
        int idx = i * 256 + tid;                 // = t*32 + c
        sBC[idx] = xdbl[(long)(row0 + (idx >> 5)) * XDBL_LD + DTRANK + (idx & 31)];
    }
    __syncthreads();

    float A[DSTATE];
    const float4* Ap = (const float4*)(A_log + d * DSTATE);
    #pragma unroll
    for (int i = 0; i < 4; ++i) {
        float4 v = Ap[i];
        A[i*4+0] = -__expf(v.x); A[i*4+1] = -__expf(v.y);
        A[i*4+2] = -__expf(v.z); A[i*4+3] = -__expf(v.w);
    }
    const float Dd = Dp[d];

    float h[DSTATE];
    const float4* Hp = (const float4*)(hin + ((long)(b * NCH + k) * DINNER + d) * DSTATE);
    #pragma unroll
    for (int i = 0; i < 4; ++i) {
        float4 v = Hp[i];
        h[i*4+0] = v.x; h[i*4+1] = v.y; h[i*4+2] = v.z; h[i*4+3] = v.w;
    }

    for (int t = 0; t < CHUNK; ++t) {
        const long row = row0 + t;
        const float dt = bf2f(delta[row * DINNER + d]);
        const float xv = bf2f(xc[row * DINNER + d]);
        const float dx = dt * xv;
        float yt = 0.f;
        #pragma unroll
        for (int s = 0; s < DSTATE; ++s) {
            float dA = __expf(dt * A[s]);
            h[s] = h[s] * dA + dx * sBC[t * 32 + s];
            yt += h[s] * sBC[t * 32 + 16 + s];
        }
        yt += xv * Dd;
        const float zv = bf2f(xz[row * 8192 + DINNER + d]);
        yt *= zv / (1.f + __expf(-zv));
        y[row * DINNER + d] = f2bf(yt);
    }
}

// ---------------------------------------------------------------------------
extern "C" void kernel_launch(void* const* d_in, const int* in_sizes, int n_in,
                              void* d_out, int out_size, void* d_ws, size_t ws_size,
                              hipStream_t stream)
{
    const float* hidden    = (const float*)d_in[0];
    const float* in_proj   = (const float*)d_in[1];
    const float* conv_w    = (const float*)d_in[2];
    const float* conv_b    = (const float*)d_in[3];
    const float* x_proj    = (const float*)d_in[4];
    const float* dt_proj_w = (const float*)d_in[5];
    const float* dt_proj_b = (const float*)d_in[6];
    const float* A_log     = (const float*)d_in[7];
    const float* Dp        = (const float*)d_in[8];
    const float* out_proj  = (const float*)d_in[9];
    float* out = (float*)d_out;

    // Workspace layout (bytes, all 16B aligned)
    char* ws = (char*)d_ws;
    ushort* xz_h    = (ushort*)(ws);                // 32 MiB  (dead after scan_p3)
    ushort* xc      = (ushort*)(ws + 33554432);     // 16 MiB  (dead after scan_p3)
    ushort* xpp     = (ushort*)(ws + 50331648);     // 2 MiB
    float*  xdbl    = (float*)(ws + 52428800);      // 2 MiB   (dead after scan_p3)
    ushort* xdblh   = (ushort*)(ws + 54525952);     // 1 MiB
    ushort* delta_h = (ushort*)(ws + 55574528);     // 16 MiB  (dead after scan_p3)
    ushort* yb      = (ushort*)(ws + 72351744);     // 16 MiB
    ushort* hid_h   = (ushort*)(ws + 89128960);     // 8 MiB
    // 32 MiB multi-use region at 97517568 (time-disjoint)
    ushort* inp_h   = (ushort*)(ws + 97517568);
    float*  parts   = (float*)(ws + 97517568);
    float*  Hbuf    = (float*)(ws + 97517568);
    float*  sumdt   = (float*)(ws + 105906176);
    ushort* dtp_h   = (ushort*)(ws + 131072000);    // 1 MiB
    ushort* outp_h  = (ushort*)(ws + 132120576);    // 16 MiB
    float*  parts2  = (float*)(ws);                 // 4 x 16 MiB, aliases dead bufs

    const int M = BB * LL;  // 2048

    // 0) all f32 -> bf16 conversions + x_proj pad, one dispatch
    cvt_all<<<30208, 256, 0, stream>>>(
        (const float4*)hidden, (const float4*)in_proj, (const float4*)dt_proj_w,
        (const float4*)out_proj, (const float4*)x_proj,
        (us4*)hid_h, (us4*)inp_h, (us4*)dtp_h, (us4*)outp_h, (us4*)xpp);

    // 1) xz = hidden @ in_proj^T   (2048x8192 bf16) — 4-phase m201 topology
    gemm_nt256<false, true><<<dim3(8192 / 256, M / 256), 512, 0, stream>>>(
        hid_h, DMODEL, inp_h, DMODEL, nullptr, xz_h, 8192, DMODEL);

    // 2) x_conv = silu(causal_conv(x) + conv_b)
    conv_silu_kernel<<<(M * DINNER) / 256, 256, 0, stream>>>(xz_h, conv_w, conv_b, xc);

    // 3) x_dbl = x_conv @ x_proj_pad^T, K split 16x256 -> partials -> reduce
    gemm_nt<0, true, false><<<dim3(XDBL_LD / 128, M / 128, 16), 256, 0, stream>>>(
        xc, DINNER, xpp, DINNER, parts, nullptr, XDBL_LD, DINNER / 16, nullptr);
    reduce_k<16, true><<<(M * XDBL_LD / 4 + 255) / 256, 256, 0, stream>>>(
        (const float4*)parts, (long)M * XDBL_LD / 4, M * XDBL_LD / 4,
        (float4*)xdbl, (us4*)xdblh);

    // 4) delta = softplus(dt_lo @ dt_proj_w^T + dt_proj_b) — single-shot
    gemm_delta<<<dim3(DINNER / 256, M / 128), 512, 0, stream>>>(
        xdblh, dtp_h, delta_h, dt_proj_b);

    // 5) chunked selective scan + D-skip + silu(z) gating -> y (bf16)
    scan_p1<<<dim3(DINNER / 256, NCH, BB), 256, 0, stream>>>(
        delta_h, xc, xdbl, A_log, Hbuf, sumdt);
    scan_p2<<<(BB * DINNER * DSTATE) / 256, 256, 0, stream>>>(
        A_log, sumdt, Hbuf);
    scan_p3<<<dim3(DINNER / 256, NCH, BB), 256, 0, stream>>>(
        delta_h, xc, xdbl, xz_h, A_log, Dp, Hbuf, yb);

    // 6) out = y @ out_proj^T, K split 4x1024 -> partials -> reduce
    gemm_nt256<true, false><<<dim3(DMODEL / 256, M / 256, 4), 512, 0, stream>>>(
        yb, DINNER, outp_h, DINNER, parts2, nullptr, DMODEL, DINNER / 4);
    reduce_k<4, false><<<(M * DMODEL / 4 + 255) / 256, 256, 0, stream>>>(
        (const float4*)parts2, (long)M * DMODEL / 4, M * DMODEL / 4,
        (float4*)out, nullptr);
}